// Round 16
// baseline (164.228 us; speedup 1.0000x reference)
//
#include <hip/hip_runtime.h>

#define B_   128
#define L_   196
#define ENC_ 2048
#define DEC_ 512
#define ATT_ 512
#define M_   (B_ * L_)   // 25088

typedef _Float16 f16x8 __attribute__((ext_vector_type(8)));
typedef __fp16   h16x2 __attribute__((ext_vector_type(2)));
typedef float    f32x4 __attribute__((ext_vector_type(4)));

// Async global->LDS DMA, 16B per lane. LDS dest is wave-uniform base + lane*16
// (our per-lane dests are exactly base+lane*16 -> consistent). Global src is
// per-lane (carries the swizzle).
__device__ __forceinline__ void gload16(const float* g, float* l) {
    __builtin_amdgcn_global_load_lds(
        (const __attribute__((address_space(1))) void*)g,
        (__attribute__((address_space(3))) void*)l, 16, 0, 0);
}

// ---------------- ws layout ----------------
// [0,          262144)   dec_map  f32 [128][512]
// [262144,    2359296)   WeTs     f16 tiled: [ntile=4][kt=64][k8=4][row=128] x f16x8 unit
// [2359296,   2760704)   partial  f32 [4][25088]

__global__ void wets_kernel(const float* __restrict__ We, _Float16* __restrict__ WeTs) {
    int u = blockIdx.x * 256 + threadIdx.x;     // 131072 units
    int row = u & 127;
    int k8  = (u >> 7) & 3;
    int kt  = (u >> 9) & 63;
    int nt  = u >> 15;
    int n  = nt * 128 + row;
    int k0 = kt * 32 + k8 * 8;
    f16x8 h;
#pragma unroll
    for (int j = 0; j < 8; ++j) h[j] = (_Float16)We[(k0 + j) * ATT_ + n];
    *reinterpret_cast<f16x8*>(WeTs + (size_t)u * 8) = h;
}

__global__ void decmap_kernel(const float* __restrict__ dh, const float* __restrict__ Wd,
                              const float* __restrict__ bd, float* __restrict__ dec) {
    int b = blockIdx.x;       // 128
    int a = threadIdx.x;      // 512
    float acc = bd[a];
    const float* dhp = dh + b * DEC_;
#pragma unroll 8
    for (int k = 0; k < DEC_; ++k) acc += dhp[k] * Wd[k * ATT_ + a];
    dec[b * ATT_ + a] = acc;
}

// Fused GEMM, m97-style: 256x128 tile, BK=32, A staged fp32 via
// global_load_lds DMA (no VGPR round-trip, no staging register sets ->
// VGPR fits 128 -> 2 blocks/CU, 4 waves/SIMD, grid 392 single round).
// LDS A layout: linear 16B units u = row*8 + k4slot, with PRE-SWIZZLED GLOBAL
// source: slot k4slot holds k4_data = k4slot ^ (row&7) (within-128B-line
// permutation -> coalescing intact). Frag reads then hit all 32 banks.
// fp32->f16 conversion happens at fragment-read time (4 cvt_pkrtz / frag).
// B direct global(L2)->reg from pre-tiled WeTs, issued B-FIRST each phase so
// MFMA's in-order vmcnt wait doesn't drain the just-issued DMA.
// Plain __syncthreads (vmcnt0 drain) per phase — m97 structure.
__global__ __launch_bounds__(512, 4)
void gemm_score_kernel(const float* __restrict__ enc,
                       const _Float16* __restrict__ WeTs,
                       const float* __restrict__ be,
                       const float* __restrict__ wa,
                       const float* __restrict__ dec,
                       float* __restrict__ partial) {
    __shared__ __align__(16) float Abuf0[8192];   // 32KB: 2048 units x 16B
    __shared__ __align__(16) float Abuf1[8192];
    __shared__ float red[2][256];

    // XCD swizzle: 392 = 8 x 49; 4 ntile-siblings of one mtile share an XCD.
    int bid = blockIdx.x;
    int sid = (bid & 7) * 49 + (bid >> 3);           // bijective on [0,392)
    int mtile = sid >> 2;                            // 0..97 (256-row tiles)
    int ntile = sid & 3;                             // 0..3  (128-col tiles)

    int tid  = threadIdx.x;
    int lane = tid & 63, wid = tid >> 6;             // 8 waves
    int wm = wid >> 1, wn = wid & 1;                 // 4 x 2, wave = 64x64
    int l15 = lane & 15, lg = lane >> 4;

    // A DMA source: thread covers slots u = i*512+tid, i=0..3.
    // row(u) = u>>3 = i*64 + (tid>>3); k4slot = tid&7;
    // k4_data = k4slot ^ (row&7) = (tid&7) ^ ((tid>>3)&7)  (i*64 = 0 mod 8)
    int r0  = tid >> 3;
    int k4d = (tid & 7) ^ (r0 & 7);
    const float* ags = enc + (size_t)(mtile * 256 + r0) * ENC_ + k4d * 4;
    // lds float base for inst i: (i*512 + tid)*4

    // B fragment source: WeTs unit (ntile, kt, k8=lg, row = wn*64+ni*16+l15)
    const _Float16* bfr = WeTs +
        ((size_t)ntile * 64 * 4 * 128 + (size_t)lg * 128 + wn * 64 + l15) * 8;
    // per-kt stride in halves: 4096; per-ni: 16*8

    // A frag read: row = wm*64+mi*16+l15; lo unit = row*8 + (2lg ^ (l15&7)),
    // hi unit = row*8 + ((2lg+1) ^ (l15&7))   [row&7 == l15&7]
    int xorv = l15 & 7;
    int lo_u[4], hi_u[4];
#pragma unroll
    for (int mi = 0; mi < 4; ++mi) {
        int row = wm * 64 + mi * 16 + l15;
        lo_u[mi] = (row * 8 + ((2 * lg) ^ xorv)) * 4;       // float idx
        hi_u[mi] = (row * 8 + ((2 * lg + 1) ^ xorv)) * 4;
    }

    f32x4 acc[4][4];
#pragma unroll
    for (int mi = 0; mi < 4; ++mi)
#pragma unroll
        for (int ni = 0; ni < 4; ++ni) acc[mi][ni] = (f32x4){0.f, 0.f, 0.f, 0.f};

    f16x8 bf[4];

    auto stage = [&](float* buf, int kt) {
        const float* g = ags + kt * 32;
#pragma unroll
        for (int i = 0; i < 4; ++i)
            gload16(g + (size_t)i * 64 * ENC_, buf + (i * 512 + tid) * 4);
    };
    auto loadB = [&](int kt) {
        const _Float16* s = bfr + (size_t)kt * 4096;
#pragma unroll
        for (int ni = 0; ni < 4; ++ni)
            bf[ni] = *reinterpret_cast<const f16x8*>(s + ni * 16 * 8);
    };
    auto compute = [&](const float* buf) {
        f16x8 af[4];
#pragma unroll
        for (int mi = 0; mi < 4; ++mi) {
            f32x4 lo = *reinterpret_cast<const f32x4*>(buf + lo_u[mi]);
            f32x4 hi = *reinterpret_cast<const f32x4*>(buf + hi_u[mi]);
            union { h16x2 h2[4]; f16x8 h8; } cv;
            cv.h2[0] = __builtin_amdgcn_cvt_pkrtz(lo[0], lo[1]);
            cv.h2[1] = __builtin_amdgcn_cvt_pkrtz(lo[2], lo[3]);
            cv.h2[2] = __builtin_amdgcn_cvt_pkrtz(hi[0], hi[1]);
            cv.h2[3] = __builtin_amdgcn_cvt_pkrtz(hi[2], hi[3]);
            af[mi] = cv.h8;
        }
        __builtin_amdgcn_s_setprio(1);
#pragma unroll
        for (int mi = 0; mi < 4; ++mi)
#pragma unroll
            for (int ni = 0; ni < 4; ++ni)
                acc[mi][ni] = __builtin_amdgcn_mfma_f32_16x16x32_f16(
                    af[mi], bf[ni], acc[mi][ni], 0, 0, 0);
        __builtin_amdgcn_s_setprio(0);
    };

    // prologue: DMA tile 0 -> buf0
    stage(Abuf0, 0);
    __syncthreads();

    for (int kt2 = 0; kt2 < 32; ++kt2) {
        int kt = kt2 * 2;
        // even phase: compute buf0(kt); stage kt+1 -> buf1
        loadB(kt);                                 // B first (vmcnt ordering)
        __builtin_amdgcn_sched_barrier(0);
        stage(Abuf1, kt + 1);                      // DMA after B
        compute(Abuf0);
        __syncthreads();
        // odd phase: compute buf1(kt+1); stage kt+2 -> buf0
        loadB(kt + 1);
        __builtin_amdgcn_sched_barrier(0);
        if (kt2 < 31) stage(Abuf0, kt + 2);
        compute(Abuf1);
        __syncthreads();
    }

    // Epilogue: x = acc + be[n] + dec[b][n]; t = tanh(x); rowsum += t*wa[n]
    float rsum[4][4];
#pragma unroll
    for (int mi = 0; mi < 4; ++mi)
#pragma unroll
        for (int j = 0; j < 4; ++j) rsum[mi][j] = 0.f;

    int rb = mtile * 256 + wm * 64;
    int nb = ntile * 128 + wn * 64;
#pragma unroll
    for (int ni = 0; ni < 4; ++ni) {
        int n = nb + ni * 16 + l15;
        float wav = wa[n];
        float bev = be[n];
#pragma unroll
        for (int mi = 0; mi < 4; ++mi) {
#pragma unroll
            for (int j = 0; j < 4; ++j) {
                int row = rb + mi * 16 + lg * 4 + j;    // C/D: col=lane&15, row=(lane>>4)*4+reg
                int b = row / L_;
                float x = acc[mi][ni][j] + bev + dec[b * ATT_ + n];
                float e = __expf(2.0f * x);
                float t = 1.0f - 2.0f / (e + 1.0f);     // tanh(x), inf-safe
                rsum[mi][j] += t * wav;
            }
        }
    }
#pragma unroll
    for (int mi = 0; mi < 4; ++mi) {
#pragma unroll
        for (int j = 0; j < 4; ++j) {
            float v = rsum[mi][j];
            v += __shfl_xor(v, 1);
            v += __shfl_xor(v, 2);
            v += __shfl_xor(v, 4);
            v += __shfl_xor(v, 8);
            if (l15 == 0) red[wn][wm * 64 + mi * 16 + lg * 4 + j] = v;
        }
    }
    __syncthreads();
    if (tid < 256)
        partial[(size_t)ntile * M_ + mtile * 256 + tid] = red[0][tid] + red[1][tid];
}

// softmax over L per batch row. ba cancels in softmax -> skipped.
__global__ void softmax_kernel(const float* __restrict__ partial, float* __restrict__ alphas) {
    int b = blockIdx.x, t = threadIdx.x;     // 128 blocks x 256 threads
    int lane = t & 63, wid = t >> 6;
    __shared__ float red[4];
    float s = 0.f, val = -1e30f;
    if (t < L_) {
        int r = b * L_ + t;
        s = partial[r] + partial[M_ + r] + partial[2 * M_ + r] + partial[3 * M_ + r];
        val = s;
    }
    float m = val;
#pragma unroll
    for (int off = 1; off < 64; off <<= 1) m = fmaxf(m, __shfl_xor(m, off));
    if (lane == 0) red[wid] = m;
    __syncthreads();
    m = fmaxf(fmaxf(red[0], red[1]), fmaxf(red[2], red[3]));
    float e = (t < L_) ? __expf(s - m) : 0.f;
    float sum = e;
#pragma unroll
    for (int off = 1; off < 64; off <<= 1) sum += __shfl_xor(sum, off);
    __syncthreads();
    if (lane == 0) red[wid] = sum;
    __syncthreads();
    sum = red[0] + red[1] + red[2] + red[3];
    if (t < L_) alphas[b * L_ + t] = e / sum;
}

// context[b][e] = sum_l alphas[b][l] * enc[b][l][e]   (memory-bound pass)
__global__ void context_kernel(const float* __restrict__ enc, const float* __restrict__ alphas,
                               float* __restrict__ ctx) {
    int b = blockIdx.x >> 2;                  // 128 b x 4 e-chunks = 512 blocks
    int ec = blockIdx.x & 3;
    int e = ec * 512 + threadIdx.x * 2;
    const float* ep = enc + (size_t)b * L_ * ENC_ + e;
    const float* ap = alphas + b * L_;
    float ax = 0.f, ay = 0.f;
#pragma unroll 4
    for (int l = 0; l < L_; ++l) {
        float a = ap[l];
        float2 v = *reinterpret_cast<const float2*>(ep + (size_t)l * ENC_);
        ax += a * v.x;
        ay += a * v.y;
    }
    float2 r; r.x = ax; r.y = ay;
    *reinterpret_cast<float2*>(&ctx[b * ENC_ + e]) = r;
}

extern "C" void kernel_launch(void* const* d_in, const int* in_sizes, int n_in,
                              void* d_out, int out_size, void* d_ws, size_t ws_size,
                              hipStream_t stream) {
    const float* enc = (const float*)d_in[0];
    const float* dh  = (const float*)d_in[1];
    const float* We  = (const float*)d_in[2];
    const float* be  = (const float*)d_in[3];
    const float* Wd  = (const float*)d_in[4];
    const float* bd  = (const float*)d_in[5];
    const float* wa  = (const float*)d_in[6];
    // d_in[7] = ba: shifts all scores equally -> cancels in softmax, unused.

    float* out    = (float*)d_out;
    float* ctx    = out;               // [128][2048]
    float* alphas = out + B_ * ENC_;   // [128][196]

    char* ws = (char*)d_ws;
    float*    dec     = (float*)ws;                            // 256 KiB
    _Float16* WeTs    = (_Float16*)(ws + 262144);              // 2 MiB
    float*    partial = (float*)(ws + 262144 + 2097152);       // 392 KiB

    hipLaunchKernelGGL(wets_kernel,       dim3(512),  dim3(256), 0, stream, We, WeTs);
    hipLaunchKernelGGL(decmap_kernel,     dim3(128),  dim3(512), 0, stream, dh, Wd, bd, dec);
    hipLaunchKernelGGL(gemm_score_kernel, dim3(392),  dim3(512), 0, stream, enc, WeTs, be, wa, dec, partial);
    hipLaunchKernelGGL(softmax_kernel,    dim3(128),  dim3(256), 0, stream, partial, alphas);
    hipLaunchKernelGGL(context_kernel,    dim3(512),  dim3(256), 0, stream, enc, alphas, ctx);
}